// Round 8
// baseline (11428.225 us; speedup 1.0000x reference)
//
#include <hip/hip_runtime.h>
#include <stdint.h>

#define B_ 256
#define S_ 512
#define H_ 256
#define G_ 1024
#define CHUNK 32
#define NCHUNK (S_ / CHUNK)

typedef __attribute__((ext_vector_type(8))) short bf16x8;
typedef __attribute__((ext_vector_type(4))) float f32x4;

__device__ __forceinline__ unsigned short f2bf(float f) {
    unsigned u = __builtin_bit_cast(unsigned, f);
    unsigned r = u + 0x7fffu + ((u >> 16) & 1u);
    return (unsigned short)(r >> 16);
}
__device__ __forceinline__ float bf2f(unsigned short v) {
    return __builtin_bit_cast(float, (unsigned)v << 16);
}
__device__ __forceinline__ float bfbits_lo(unsigned v) {
    return __builtin_bit_cast(float, (unsigned)(v << 16));
}
__device__ __forceinline__ float bfbits_hi(unsigned v) {
    return __builtin_bit_cast(float, v & 0xffff0000u);
}
__device__ __forceinline__ float sigmoidf_(float x) { return 1.f / (1.f + __expf(-x)); }
__device__ __forceinline__ float tanhf_(float x) { return 2.f / (1.f + __expf(-2.f * x)) - 1.f; }

// async global->LDS, 16B per lane; LDS dest wave-uniform base (+ lane*16 implicit)
__device__ __forceinline__ void gload_lds16(const void* g, void* s) {
    __builtin_amdgcn_global_load_lds((const __attribute__((address_space(1))) unsigned int*)g,
                                     (__attribute__((address_space(3))) unsigned int*)s, 16, 0, 0);
}

// ---------------- prep: weights -> fragment-major bf16 ----------------
// Wp[nt][kk][lane][i] = W[k][n], k = kk*32 + (lane>>4)*8 + i, n = nt*16 + (lane&15)
__global__ void prep_w(const float* __restrict__ W, unsigned short* __restrict__ Wp, int NT) {
    int tid = blockIdx.x * 256 + threadIdx.x;
    int total = NT * 8 * 64;
    if (tid >= total) return;
    int l = tid & 63, kk = (tid >> 6) & 7, nt = tid >> 9;
    int n = nt * 16 + (l & 15);
    int k0 = kk * 32 + (l >> 4) * 8;
    int N = NT * 16;
    unsigned short v[8];
#pragma unroll
    for (int i = 0; i < 8; i++) v[i] = f2bf(W[(size_t)(k0 + i) * N + n]);
    uint4 o;
    o.x = (unsigned)v[0] | ((unsigned)v[1] << 16);
    o.y = (unsigned)v[2] | ((unsigned)v[3] << 16);
    o.z = (unsigned)v[4] | ((unsigned)v[5] << 16);
    o.w = (unsigned)v[6] | ((unsigned)v[7] << 16);
    *(uint4*)(Wp + (size_t)tid * 8) = o;
}

__global__ void prep_decay(const float* __restrict__ x, float* __restrict__ dec, int n) {
    int i = blockIdx.x * 256 + threadIdx.x;
    if (i < n) dec[i] = 1.f / __logf(2.718281828459045f + x[(size_t)i * H_ + (H_ - 1)]);
}

// ---------------- xg GEMM body (unchanged) ----------------
template <bool SRCF32>
__device__ void gemm_body(const void* __restrict__ src, const unsigned short* __restrict__ Wp,
                          const float* __restrict__ bias, unsigned short* __restrict__ xgp,
                          int chunk, short* Albs) {
    const int tid = threadIdx.x;
    const int bx = blockIdx.x;
    const int by = blockIdx.y;
    const int r0 = bx * 128;
    const int t_loc = r0 >> 8;
    const int b0 = r0 & 255;
    const int sg = chunk * CHUNK + t_loc;
    {
        const int m = tid >> 1, kh = tid & 1;
        const size_t rowbase = ((size_t)(b0 + m) * S_ + sg) * H_ + kh * 128;
        if constexpr (SRCF32) {
            const float* p = (const float*)src + rowbase;
#pragma unroll
            for (int jo = 0; jo < 16; jo++) {
                int k = kh * 128 + jo * 8;
                float4 a = *(const float4*)(p + jo * 8);
                float4 b = *(const float4*)(p + jo * 8 + 4);
                int slot = ((m >> 4) * 8 + (k >> 5)) * 64 + ((m & 15) | (((k >> 3) & 3) << 4));
                uint4 o;
                o.x = (unsigned)f2bf(a.x) | ((unsigned)f2bf(a.y) << 16);
                o.y = (unsigned)f2bf(a.z) | ((unsigned)f2bf(a.w) << 16);
                o.z = (unsigned)f2bf(b.x) | ((unsigned)f2bf(b.y) << 16);
                o.w = (unsigned)f2bf(b.z) | ((unsigned)f2bf(b.w) << 16);
                *(uint4*)&Albs[slot * 8] = o;
            }
        } else {
            const unsigned short* p = (const unsigned short*)src + rowbase;
#pragma unroll
            for (int jo = 0; jo < 16; jo++) {
                int k = kh * 128 + jo * 8;
                uint4 o = *(const uint4*)(p + jo * 8);
                int slot = ((m >> 4) * 8 + (k >> 5)) * 64 + ((m & 15) | (((k >> 3) & 3) << 4));
                *(uint4*)&Albs[slot * 8] = o;
            }
        }
    }
    __syncthreads();
    const int w = tid >> 6, l = tid & 63;
    const int wm = w >> 1, wn = w & 1;
    const int col = l & 15;
    float bv[4];
#pragma unroll
    for (int q = 0; q < 4; q++) bv[q] = bias[(by * 8 + wn * 4 + q) * 16 + col];
    f32x4 acc[4][4];
#pragma unroll
    for (int mi = 0; mi < 4; mi++)
#pragma unroll
        for (int q = 0; q < 4; q++) {
            acc[mi][q][0] = bv[q]; acc[mi][q][1] = bv[q];
            acc[mi][q][2] = bv[q]; acc[mi][q][3] = bv[q];
        }
    const bf16x8* Wp8 = (const bf16x8*)Wp;
#pragma unroll
    for (int kk = 0; kk < 8; kk++) {
        bf16x8 af[4], bfr[4];
#pragma unroll
        for (int mi = 0; mi < 4; mi++)
            af[mi] = *(const bf16x8*)&Albs[(((wm * 4 + mi) * 8 + kk) * 64 + l) * 8];
#pragma unroll
        for (int q = 0; q < 4; q++)
            bfr[q] = Wp8[((size_t)(by * 8 + wn * 4 + q) * 8 + kk) * 64 + l];
#pragma unroll
        for (int mi = 0; mi < 4; mi++)
#pragma unroll
            for (int q = 0; q < 4; q++)
                acc[mi][q] = __builtin_amdgcn_mfma_f32_16x16x32_bf16(af[mi], bfr[q], acc[mi][q], 0, 0, 0);
    }
    const int rblk0 = r0 >> 4;
#pragma unroll
    for (int mi = 0; mi < 4; mi++) {
        int rowblk = rblk0 + wm * 4 + mi;
#pragma unroll
        for (int q = 0; q < 4; q++) {
            int qg = by * 8 + wn * 4 + q;
            uint2 o;
            o.x = (unsigned)f2bf(acc[mi][q][0]) | ((unsigned)f2bf(acc[mi][q][1]) << 16);
            o.y = (unsigned)f2bf(acc[mi][q][2]) | ((unsigned)f2bf(acc[mi][q][3]) << 16);
            *(uint2*)&xgp[(((size_t)rowblk * 64 + qg) * 64 + l) * 4] = o;
        }
    }
}

__global__ __launch_bounds__(256) void gemm_dual(const float* __restrict__ x,
                                                 const unsigned short* __restrict__ y0bf,
                                                 const unsigned short* __restrict__ Wp0,
                                                 const float* __restrict__ bias0,
                                                 const unsigned short* __restrict__ Wp1,
                                                 const float* __restrict__ bias1,
                                                 unsigned short* __restrict__ xgpA,
                                                 unsigned short* __restrict__ xgpB, int c0, int c1) {
    extern __shared__ short Albs[];  // 64 KB
    if (blockIdx.z == 0) {
        if (c0 < 0) return;
        gemm_body<true>(x, Wp0, bias0, xgpA, c0, Albs);
    } else {
        if (c1 < 0) return;
        gemm_body<false>(y0bf, Wp1, bias1, xgpB, c1, Albs);
    }
}

// ---------------- recurrent scan (R5 production, unchanged) ----------------
template <bool ISL0>
__device__ void rec_run(const unsigned short* __restrict__ xgp, const bf16x8* __restrict__ Whp8,
                        const bf16x8* __restrict__ Wdp8, const float* __restrict__ bd,
                        const float* __restrict__ dec_in, void* __restrict__ yout,
                        float* __restrict__ dec_out, unsigned short* __restrict__ h_state,
                        float* __restrict__ c_state, int chunk, int bblk, char* smem) {
    short* stage = (short*)smem;           // [2][16 waves][4 frags * 512 shorts] = 128 KB
    short* hb = (short*)(smem + 131072);   // [16][256] bf16
    short* cb = (short*)(smem + 139264);   // [16][256] bf16
    const int tid = threadIdx.x;           // 0..1023
    const int w = tid >> 6, l = tid & 63;
    const int lgrp = l >> 4, col = l & 15;
    const int b0 = bblk * 16;
    const int n = w * 16 + col;
    const float bdv = bd[n];

    bf16x8 wd[8];
#pragma unroll
    for (int kk = 0; kk < 8; kk++) wd[kk] = Wdp8[((size_t)w * 8 + kk) * 64 + l];

    float creg[4];
    if (chunk == 0) {
#pragma unroll
        for (int r = 0; r < 4; r++) creg[r] = 0.f;
        for (int i = tid; i < 4096; i += 1024) { hb[i] = 0; cb[i] = 0; }
    } else {
#pragma unroll
        for (int i = 0; i < 4; i++) {
            int idx = tid + i * 1024;
            int row = idx >> 8, nn = idx & 255;
            int sw = nn ^ ((row & 7) << 3);
            hb[row * 256 + sw] = (short)h_state[(size_t)(b0 + row) * H_ + nn];
            cb[row * 256 + sw] = (short)f2bf(c_state[(size_t)(b0 + row) * H_ + nn]);
        }
#pragma unroll
        for (int r = 0; r < 4; r++)
            creg[r] = c_state[(size_t)(b0 + lgrp * 4 + r) * H_ + n];
    }
    const uint2* xg8 = (const uint2*)xgp;
    uint2 xc[4], xn[4];
#pragma unroll
    for (int q = 0; q < 4; q++)
        xc[q] = xg8[((size_t)bblk * 64 + (q * 16 + w)) * 64 + l];
    __syncthreads();

    short* swave0 = stage + ((size_t)w) * 2048;
    short* swave1 = stage + ((size_t)(16 + w)) * 2048;
#pragma unroll
    for (int q = 0; q < 4; q++)
        gload_lds16(Whp8 + ((size_t)(q * 16 + w) * 8 + 0) * 64 + l, swave0 + q * 512);

#pragma unroll 1
    for (int t = 0; t < CHUNK; ++t) {
        const int tg = chunk * CHUNK + t;
        float dcur[4];
#pragma unroll
        for (int r = 0; r < 4; r++)
            dcur[r] = dec_in[(size_t)(b0 + lgrp * 4 + r) * S_ + tg];
        if (t + 1 < CHUNK) {
            int rb = (t + 1) * 16 + bblk;
#pragma unroll
            for (int q = 0; q < 4; q++)
                xn[q] = xg8[((size_t)rb * 64 + (q * 16 + w)) * 64 + l];
        }
        f32x4 csacc = {0.f, 0.f, 0.f, 0.f};
        f32x4 gacc[4];
#pragma unroll
        for (int q = 0; q < 4; q++) {
            uint2 v = xc[q];
            gacc[q][0] = bfbits_lo(v.x);
            gacc[q][1] = bfbits_hi(v.x);
            gacc[q][2] = bfbits_lo(v.y);
            gacc[q][3] = bfbits_hi(v.y);
        }
#pragma unroll
        for (int kk = 0; kk < 8; kk++) {
            __builtin_amdgcn_s_waitcnt(0x0F70);  // vmcnt(0)
            __builtin_amdgcn_sched_barrier(0);
            const short* sbuf = (kk & 1) ? swave1 : swave0;
            const int ha = col * 256 + ((kk * 32 + lgrp * 8) ^ ((col & 7) << 3));
            bf16x8 hf = *(const bf16x8*)&hb[ha];
            bf16x8 cf = *(const bf16x8*)&cb[ha];
            csacc = __builtin_amdgcn_mfma_f32_16x16x32_bf16(cf, wd[kk], csacc, 0, 0, 0);
#pragma unroll
            for (int q = 0; q < 4; q++) {
                bf16x8 wf = *(const bf16x8*)&sbuf[q * 512 + l * 8];
                gacc[q] = __builtin_amdgcn_mfma_f32_16x16x32_bf16(hf, wf, gacc[q], 0, 0, 0);
            }
            const int kn = (kk + 1) & 7;
            short* sdst = ((kk + 1) & 1) ? swave1 : swave0;
#pragma unroll
            for (int q = 0; q < 4; q++)
                gload_lds16(Whp8 + ((size_t)(q * 16 + w) * 8 + kn) * 64 + l, sdst + q * 512);
        }
        __syncthreads();
#pragma unroll
        for (int r = 0; r < 4; r++) {
            int row = lgrp * 4 + r;
            float cs = tanhf_(csacc[r] + bdv);
            float cadj = creg[r] - cs + cs * dcur[r];
            float iv = sigmoidf_(gacc[0][r]);
            float fv = sigmoidf_(gacc[1][r]);
            float ov = sigmoidf_(gacc[2][r]);
            float cd = tanhf_(gacc[3][r]);
            float cn = fv * cadj + iv * cd;
            float hn = ov * tanhf_(cn);
            creg[r] = cn;
            int sw = n ^ ((row & 7) << 3);
            unsigned short hnb = f2bf(hn);
            hb[row * 256 + sw] = (short)hnb;
            cb[row * 256 + sw] = (short)f2bf(cn);
            size_t yi = ((size_t)(b0 + row) * S_ + tg) * H_ + n;
            if constexpr (ISL0) {
                ((unsigned short*)yout)[yi] = hnb;
                if (w == 15 && col == 15)
                    dec_out[(size_t)(b0 + row) * S_ + tg] = 1.f / __logf(2.718281828459045f + hn);
            } else {
                ((float*)yout)[yi] = hn;
            }
            if (t == CHUNK - 1) {
                h_state[(size_t)(b0 + row) * H_ + n] = hnb;
                c_state[(size_t)(b0 + row) * H_ + n] = cn;
            }
        }
        __syncthreads();
#pragma unroll
        for (int q = 0; q < 4; q++) xc[q] = xn[q];
    }
}

__global__ __launch_bounds__(1024, 4) void rec_fused(
    const unsigned short* __restrict__ xgpA, const unsigned short* __restrict__ Whp0,
    const unsigned short* __restrict__ Wdp0, const float* __restrict__ bd0,
    const float* __restrict__ dec0, unsigned short* __restrict__ y0bf,
    float* __restrict__ dec1, unsigned short* __restrict__ hs0, float* __restrict__ cs0,
    const unsigned short* __restrict__ xgpB, const unsigned short* __restrict__ Whp1,
    const unsigned short* __restrict__ Wdp1, const float* __restrict__ bd1,
    float* __restrict__ y1, unsigned short* __restrict__ hs1, float* __restrict__ cs1,
    int c0, int c1) {
    extern __shared__ char smem[];
    int lay = blockIdx.x >> 4, bblk = blockIdx.x & 15;
    if (lay == 0) {
        if (c0 < 0) return;
        rec_run<true>(xgpA, (const bf16x8*)Whp0, (const bf16x8*)Wdp0, bd0, dec0, y0bf, dec1,
                      hs0, cs0, c0, bblk, smem);
    } else {
        if (c1 < 0) return;
        rec_run<false>(xgpB, (const bf16x8*)Whp1, (const bf16x8*)Wdp1, bd1, dec1, y1, nullptr,
                       hs1, cs1, c1, bblk, smem);
    }
}

__global__ void copy_tail(const unsigned short* __restrict__ h0, const float* __restrict__ c0,
                          const unsigned short* __restrict__ h1, const float* __restrict__ c1,
                          float* __restrict__ out) {
    int i = blockIdx.x * 256 + threadIdx.x;
    if (i >= 4 * 65536) return;
    int which = i >> 16, j = i & 65535;
    float v = which == 0 ? bf2f(h0[j]) : which == 1 ? c0[j] : which == 2 ? bf2f(h1[j]) : c1[j];
    out[i] = v;
}

// ================= DIAGNOSTIC PROBES (write only to dead scratch) =================
// MODE 0 full(R5)  1 counted-vmcnt  2 no-DMA  3 no-global  4 skeleton(no MFMA)
template <int MODE, int STEPS>
__device__ __forceinline__ void probe_body(const unsigned short* __restrict__ xgp,
                                           const bf16x8* __restrict__ Whp8,
                                           const bf16x8* __restrict__ Wdp8,
                                           const float* __restrict__ bd,
                                           const float* __restrict__ dec_in,
                                           float* __restrict__ ys, float* __restrict__ chk,
                                           char* smem) {
    short* stage = (short*)smem;
    short* hb = (short*)(smem + 131072);
    short* cb = (short*)(smem + 139264);
    float* decs = (float*)(smem + 147456);
    const int tid = threadIdx.x;
    const int w = tid >> 6, l = tid & 63;
    const int lgrp = l >> 4, col = l & 15;
    const int bblk = blockIdx.x & 15;
    const int b0 = bblk * 16;
    const int n = w * 16 + col;
    const float bdv = bd[n];
    bf16x8 wd[8];
#pragma unroll
    for (int kk = 0; kk < 8; kk++) wd[kk] = Wdp8[((size_t)w * 8 + kk) * 64 + l];
    float creg[4];
#pragma unroll
    for (int r = 0; r < 4; r++) creg[r] = 0.f;
    for (int i = tid; i < 4096; i += 1024) { hb[i] = 0; cb[i] = 0; }
    if (MODE >= 3 && tid < 512) {
        int row = tid >> 5, tt = tid & 31;
        decs[tt * 17 + row] = dec_in[(size_t)(b0 + row) * S_ + tt];
    }
    const uint2* xg8 = (const uint2*)xgp;
    uint2 xc[4], xn2[4];
#pragma unroll
    for (int q = 0; q < 4; q++) xc[q] = xg8[((size_t)bblk * 64 + (q * 16 + w)) * 64 + l];
    __syncthreads();
    short* s0 = stage + (size_t)w * 2048;
    short* s1 = stage + (size_t)(16 + w) * 2048;
    if (MODE <= 1) {
#pragma unroll
        for (int q = 0; q < 4; q++)
            gload_lds16(Whp8 + ((size_t)(q * 16 + w) * 8 + 0) * 64 + l, s0 + q * 512);
    }
#pragma unroll 1
    for (int t = 0; t < STEPS; ++t) {
        const int tg = t & 31;
        float dcur[4];
        if (MODE <= 2) {
#pragma unroll
            for (int r = 0; r < 4; r++) dcur[r] = dec_in[(size_t)(b0 + lgrp * 4 + r) * S_ + tg];
        } else {
#pragma unroll
            for (int r = 0; r < 4; r++) dcur[r] = decs[tg * 17 + lgrp * 4 + r];
        }
        if (MODE <= 2) {
            int rb = ((t + 1) & 31) * 16 + bblk;
#pragma unroll
            for (int q = 0; q < 4; q++) xn2[q] = xg8[((size_t)rb * 64 + (q * 16 + w)) * 64 + l];
        }
        f32x4 csacc = {0.f, 0.f, 0.f, 0.f};
        f32x4 gacc[4];
#pragma unroll
        for (int q = 0; q < 4; q++) {
            uint2 v = xc[q];
            gacc[q][0] = bfbits_lo(v.x);
            gacc[q][1] = bfbits_hi(v.x);
            gacc[q][2] = bfbits_lo(v.y);
            gacc[q][3] = bfbits_hi(v.y);
        }
        if (MODE == 4) {  // keep per-step variation + hb/cb read dependence (anti-DCE)
#pragma unroll
            for (int r = 0; r < 4; r++) {
                csacc[r] += dcur[r] * 0.001f;
                creg[r] += bf2f((unsigned short)hb[(tid * 4 + r + t) & 4095]) * 1e-30f +
                           bf2f((unsigned short)cb[(tid * 4 + r + t * 3) & 4095]) * 1e-30f;
            }
        }
        if (MODE <= 3) {
#pragma unroll
            for (int kk = 0; kk < 8; kk++) {
                if (MODE == 0) {
                    __builtin_amdgcn_s_waitcnt(0x0F70);  // vmcnt(0)
                    __builtin_amdgcn_sched_barrier(0);
                } else if (MODE == 1) {
                    const int kn = (kk + 1) & 7;
                    short* sd = ((kk + 1) & 1) ? s1 : s0;
#pragma unroll
                    for (int q = 0; q < 4; q++)
                        gload_lds16(Whp8 + ((size_t)(q * 16 + w) * 8 + kn) * 64 + l, sd + q * 512);
                    asm volatile("s_waitcnt vmcnt(4)" ::: "memory");
                    __builtin_amdgcn_sched_barrier(0);
                }
                const short* sbuf = (kk & 1) ? s1 : s0;
                const int ha = col * 256 + ((kk * 32 + lgrp * 8) ^ ((col & 7) << 3));
                bf16x8 hf = *(const bf16x8*)&hb[ha];
                bf16x8 cf = *(const bf16x8*)&cb[ha];
                csacc = __builtin_amdgcn_mfma_f32_16x16x32_bf16(cf, wd[kk], csacc, 0, 0, 0);
#pragma unroll
                for (int q = 0; q < 4; q++) {
                    bf16x8 wf = *(const bf16x8*)&sbuf[q * 512 + l * 8];
                    gacc[q] = __builtin_amdgcn_mfma_f32_16x16x32_bf16(hf, wf, gacc[q], 0, 0, 0);
                }
                if (MODE == 0) {
                    const int kn = (kk + 1) & 7;
                    short* sd = ((kk + 1) & 1) ? s1 : s0;
#pragma unroll
                    for (int q = 0; q < 4; q++)
                        gload_lds16(Whp8 + ((size_t)(q * 16 + w) * 8 + kn) * 64 + l, sd + q * 512);
                }
            }
        }
        __syncthreads();
#pragma unroll
        for (int r = 0; r < 4; r++) {
            int row = lgrp * 4 + r;
            float cs = tanhf_(csacc[r] + bdv);
            float cadj = creg[r] - cs + cs * dcur[r];
            float iv = sigmoidf_(gacc[0][r]);
            float fv = sigmoidf_(gacc[1][r]);
            float ov = sigmoidf_(gacc[2][r]);
            float cd = tanhf_(gacc[3][r]);
            float cn = fv * cadj + iv * cd;
            float hn = ov * tanhf_(cn);
            creg[r] = cn;
            int sw = n ^ ((row & 7) << 3);
            hb[row * 256 + sw] = (short)f2bf(hn);
            cb[row * 256 + sw] = (short)f2bf(cn);
            if (MODE <= 2)
                ys[(((size_t)(b0 + row)) * 32 + tg) * H_ + n] = hn;
        }
        __syncthreads();
        if (MODE <= 2) {
#pragma unroll
            for (int q = 0; q < 4; q++) xc[q] = xn2[q];
        }
    }
    float s = creg[0] + creg[1] + creg[2] + creg[3] + bf2f((unsigned short)hb[tid & 4095]) +
              bf2f((unsigned short)cb[(tid * 7) & 4095]);
    chk[blockIdx.x * 1024 + tid] = s;
}

#define PROBE_ARGS const unsigned short* xgp, const unsigned short* Whp, const unsigned short* Wdp, \
                   const float* bd, const float* dec_in, float* ys, float* chk
__global__ __launch_bounds__(1024, 4) void probe_full(PROBE_ARGS) {
    extern __shared__ char smem[];
    probe_body<0, 64>(xgp, (const bf16x8*)Whp, (const bf16x8*)Wdp, bd, dec_in, ys, chk, smem);
}
__global__ __launch_bounds__(1024, 4) void probe_cnt(PROBE_ARGS) {
    extern __shared__ char smem[];
    probe_body<1, 64>(xgp, (const bf16x8*)Whp, (const bf16x8*)Wdp, bd, dec_in, ys, chk, smem);
}
__global__ __launch_bounds__(1024, 4) void probe_nodma(PROBE_ARGS) {
    extern __shared__ char smem[];
    probe_body<2, 64>(xgp, (const bf16x8*)Whp, (const bf16x8*)Wdp, bd, dec_in, ys, chk, smem);
}
__global__ __launch_bounds__(1024, 4) void probe_noglb(PROBE_ARGS) {
    extern __shared__ char smem[];
    probe_body<3, 128>(xgp, (const bf16x8*)Whp, (const bf16x8*)Wdp, bd, dec_in, ys, chk, smem);
}
__global__ __launch_bounds__(1024, 4) void probe_skel(PROBE_ARGS) {
    extern __shared__ char smem[];
    probe_body<4, 128>(xgp, (const bf16x8*)Whp, (const bf16x8*)Wdp, bd, dec_in, ys, chk, smem);
}

extern "C" void kernel_launch(void* const* d_in, const int* in_sizes, int n_in, void* d_out,
                              int out_size, void* d_ws, size_t ws_size, hipStream_t stream) {
    (void)in_sizes; (void)n_in; (void)out_size; (void)ws_size;
    const float* x   = (const float*)d_in[0];
    const float* Wx0 = (const float*)d_in[1];
    const float* Wh0 = (const float*)d_in[2];
    const float* b0  = (const float*)d_in[3];
    const float* Wd0 = (const float*)d_in[4];
    const float* bd0 = (const float*)d_in[5];
    const float* Wx1 = (const float*)d_in[6];
    const float* Wh1 = (const float*)d_in[7];
    const float* b1  = (const float*)d_in[8];
    const float* Wd1 = (const float*)d_in[9];
    const float* bd1 = (const float*)d_in[10];

    char* ws = (char*)d_ws;
    size_t off = 0;
    auto take = [&](size_t bytes) { void* p = ws + off; off += (bytes + 255) & ~(size_t)255; return p; };
    unsigned short* wxp0 = (unsigned short*)take(524288);
    unsigned short* whp0 = (unsigned short*)take(524288);
    unsigned short* wdp0 = (unsigned short*)take(131072);
    unsigned short* wxp1 = (unsigned short*)take(524288);
    unsigned short* whp1 = (unsigned short*)take(524288);
    unsigned short* wdp1 = (unsigned short*)take(131072);
    float* dec0 = (float*)take(524288);
    float* dec1 = (float*)take(524288);
    unsigned short* hs0 = (unsigned short*)take(131072);
    float* cs0 = (float*)take(262144);
    unsigned short* hs1 = (unsigned short*)take(131072);
    float* cs1 = (float*)take(262144);
    unsigned short* y0bf = (unsigned short*)take(67108864);
    unsigned short* xgpA = (unsigned short*)take(16777216);
    unsigned short* xgpB = (unsigned short*)take(16777216);
    // probe scratch aliases the (dead-after-production) y0bf region; rewritten each replay
    float* probe_ys  = (float*)y0bf;                 // 8 MB
    float* probe_chk = (float*)(y0bf + 16777216);    // 64 KB at +32MB offset

    const size_t smem_rec = 147456;
    const size_t smem_probe = 149632;
    (void)hipFuncSetAttribute(reinterpret_cast<const void*>(&rec_fused),
                              hipFuncAttributeMaxDynamicSharedMemorySize, (int)smem_rec);
    (void)hipFuncSetAttribute(reinterpret_cast<const void*>(&gemm_dual),
                              hipFuncAttributeMaxDynamicSharedMemorySize, 65536);
    (void)hipFuncSetAttribute(reinterpret_cast<const void*>(&probe_full),
                              hipFuncAttributeMaxDynamicSharedMemorySize, (int)smem_probe);
    (void)hipFuncSetAttribute(reinterpret_cast<const void*>(&probe_cnt),
                              hipFuncAttributeMaxDynamicSharedMemorySize, (int)smem_probe);
    (void)hipFuncSetAttribute(reinterpret_cast<const void*>(&probe_nodma),
                              hipFuncAttributeMaxDynamicSharedMemorySize, (int)smem_probe);
    (void)hipFuncSetAttribute(reinterpret_cast<const void*>(&probe_noglb),
                              hipFuncAttributeMaxDynamicSharedMemorySize, (int)smem_probe);
    (void)hipFuncSetAttribute(reinterpret_cast<const void*>(&probe_skel),
                              hipFuncAttributeMaxDynamicSharedMemorySize, (int)smem_probe);

    prep_w<<<128, 256, 0, stream>>>(Wx0, wxp0, 64);
    prep_w<<<128, 256, 0, stream>>>(Wh0, whp0, 64);
    prep_w<<<32, 256, 0, stream>>>(Wd0, wdp0, 16);
    prep_w<<<128, 256, 0, stream>>>(Wx1, wxp1, 64);
    prep_w<<<128, 256, 0, stream>>>(Wh1, whp1, 64);
    prep_w<<<32, 256, 0, stream>>>(Wd1, wdp1, 16);
    prep_decay<<<512, 256, 0, stream>>>(x, dec0, B_ * S_);

    float* y1 = (float*)d_out;
    for (int s = 0; s <= NCHUNK; ++s) {
        int c0 = (s < NCHUNK) ? s : -1;
        int c1 = (s >= 1) ? s - 1 : -1;
        gemm_dual<<<dim3(64, 8, 2), 256, 65536, stream>>>(x, y0bf, wxp0, b0, wxp1, b1,
                                                          xgpA, xgpB, c0, c1);
        rec_fused<<<32, 1024, smem_rec, stream>>>(xgpA, whp0, wdp0, bd0, dec0, y0bf, dec1,
                                                  hs0, cs0, xgpB, whp1, wdp1, bd1, y1,
                                                  hs1, cs1, c0, c1);
    }
    copy_tail<<<1024, 256, 0, stream>>>(hs0, cs0, hs1, cs1, y1 + (size_t)B_ * S_ * H_);

    // diagnostic probes (read-only on production inputs; write dead scratch)
    probe_full<<<16, 1024, smem_probe, stream>>>(xgpA, whp0, wdp0, bd0, dec0, probe_ys, probe_chk);
    probe_cnt<<<16, 1024, smem_probe, stream>>>(xgpA, whp0, wdp0, bd0, dec0, probe_ys, probe_chk);
    probe_nodma<<<16, 1024, smem_probe, stream>>>(xgpA, whp0, wdp0, bd0, dec0, probe_ys, probe_chk);
    probe_noglb<<<16, 1024, smem_probe, stream>>>(xgpA, whp0, wdp0, bd0, dec0, probe_ys, probe_chk);
    probe_skel<<<16, 1024, smem_probe, stream>>>(xgpA, whp0, wdp0, bd0, dec0, probe_ys, probe_chk);
}

// Round 9
// 7794.954 us; speedup vs baseline: 1.4661x; 1.4661x over previous
//
#include <hip/hip_runtime.h>
#include <stdint.h>

#define B_ 256
#define S_ 512
#define H_ 256
#define G_ 1024
#define CHUNK 32
#define NCHUNK (S_ / CHUNK)

typedef __attribute__((ext_vector_type(8))) short bf16x8;
typedef __attribute__((ext_vector_type(4))) float f32x4;

__device__ __forceinline__ unsigned short f2bf(float f) {
    unsigned u = __builtin_bit_cast(unsigned, f);
    unsigned r = u + 0x7fffu + ((u >> 16) & 1u);
    return (unsigned short)(r >> 16);
}
__device__ __forceinline__ float bf2f(unsigned short v) {
    return __builtin_bit_cast(float, (unsigned)v << 16);
}
__device__ __forceinline__ float bfbits_lo(unsigned v) {
    return __builtin_bit_cast(float, (unsigned)(v << 16));
}
__device__ __forceinline__ float bfbits_hi(unsigned v) {
    return __builtin_bit_cast(float, v & 0xffff0000u);
}
__device__ __forceinline__ float sigmoidf_(float x) { return 1.f / (1.f + __expf(-x)); }
__device__ __forceinline__ float tanhf_(float x) { return 2.f / (1.f + __expf(-2.f * x)) - 1.f; }

// async global->LDS, 16B per lane; LDS dest wave-uniform base (+ lane*16 implicit)
__device__ __forceinline__ void gload_lds16(const void* g, void* s) {
    __builtin_amdgcn_global_load_lds((const __attribute__((address_space(1))) unsigned int*)g,
                                     (__attribute__((address_space(3))) unsigned int*)s, 16, 0, 0);
}

// ---------------- prep: weights -> fragment-major bf16 ----------------
// Wp[nt][kk][lane][i] = W[k][n], k = kk*32 + (lane>>4)*8 + i, n = nt*16 + (lane&15)
__global__ void prep_w(const float* __restrict__ W, unsigned short* __restrict__ Wp, int NT) {
    int tid = blockIdx.x * 256 + threadIdx.x;
    int total = NT * 8 * 64;
    if (tid >= total) return;
    int l = tid & 63, kk = (tid >> 6) & 7, nt = tid >> 9;
    int n = nt * 16 + (l & 15);
    int k0 = kk * 32 + (l >> 4) * 8;
    int N = NT * 16;
    unsigned short v[8];
#pragma unroll
    for (int i = 0; i < 8; i++) v[i] = f2bf(W[(size_t)(k0 + i) * N + n]);
    uint4 o;
    o.x = (unsigned)v[0] | ((unsigned)v[1] << 16);
    o.y = (unsigned)v[2] | ((unsigned)v[3] << 16);
    o.z = (unsigned)v[4] | ((unsigned)v[5] << 16);
    o.w = (unsigned)v[6] | ((unsigned)v[7] << 16);
    *(uint4*)(Wp + (size_t)tid * 8) = o;
}

__global__ void prep_decay(const float* __restrict__ x, float* __restrict__ dec, int n) {
    int i = blockIdx.x * 256 + threadIdx.x;
    if (i < n) dec[i] = 1.f / __logf(2.718281828459045f + x[(size_t)i * H_ + (H_ - 1)]);
}

// ---------------- xg GEMM body (unchanged) ----------------
template <bool SRCF32>
__device__ void gemm_body(const void* __restrict__ src, const unsigned short* __restrict__ Wp,
                          const float* __restrict__ bias, unsigned short* __restrict__ xgp,
                          int chunk, short* Albs) {
    const int tid = threadIdx.x;
    const int bx = blockIdx.x;
    const int by = blockIdx.y;
    const int r0 = bx * 128;
    const int t_loc = r0 >> 8;
    const int b0 = r0 & 255;
    const int sg = chunk * CHUNK + t_loc;
    {
        const int m = tid >> 1, kh = tid & 1;
        const size_t rowbase = ((size_t)(b0 + m) * S_ + sg) * H_ + kh * 128;
        if constexpr (SRCF32) {
            const float* p = (const float*)src + rowbase;
#pragma unroll
            for (int jo = 0; jo < 16; jo++) {
                int k = kh * 128 + jo * 8;
                float4 a = *(const float4*)(p + jo * 8);
                float4 b = *(const float4*)(p + jo * 8 + 4);
                int slot = ((m >> 4) * 8 + (k >> 5)) * 64 + ((m & 15) | (((k >> 3) & 3) << 4));
                uint4 o;
                o.x = (unsigned)f2bf(a.x) | ((unsigned)f2bf(a.y) << 16);
                o.y = (unsigned)f2bf(a.z) | ((unsigned)f2bf(a.w) << 16);
                o.z = (unsigned)f2bf(b.x) | ((unsigned)f2bf(b.y) << 16);
                o.w = (unsigned)f2bf(b.z) | ((unsigned)f2bf(b.w) << 16);
                *(uint4*)&Albs[slot * 8] = o;
            }
        } else {
            const unsigned short* p = (const unsigned short*)src + rowbase;
#pragma unroll
            for (int jo = 0; jo < 16; jo++) {
                int k = kh * 128 + jo * 8;
                uint4 o = *(const uint4*)(p + jo * 8);
                int slot = ((m >> 4) * 8 + (k >> 5)) * 64 + ((m & 15) | (((k >> 3) & 3) << 4));
                *(uint4*)&Albs[slot * 8] = o;
            }
        }
    }
    __syncthreads();
    const int w = tid >> 6, l = tid & 63;
    const int wm = w >> 1, wn = w & 1;
    const int col = l & 15;
    float bv[4];
#pragma unroll
    for (int q = 0; q < 4; q++) bv[q] = bias[(by * 8 + wn * 4 + q) * 16 + col];
    f32x4 acc[4][4];
#pragma unroll
    for (int mi = 0; mi < 4; mi++)
#pragma unroll
        for (int q = 0; q < 4; q++) {
            acc[mi][q][0] = bv[q]; acc[mi][q][1] = bv[q];
            acc[mi][q][2] = bv[q]; acc[mi][q][3] = bv[q];
        }
    const bf16x8* Wp8 = (const bf16x8*)Wp;
#pragma unroll
    for (int kk = 0; kk < 8; kk++) {
        bf16x8 af[4], bfr[4];
#pragma unroll
        for (int mi = 0; mi < 4; mi++)
            af[mi] = *(const bf16x8*)&Albs[(((wm * 4 + mi) * 8 + kk) * 64 + l) * 8];
#pragma unroll
        for (int q = 0; q < 4; q++)
            bfr[q] = Wp8[((size_t)(by * 8 + wn * 4 + q) * 8 + kk) * 64 + l];
#pragma unroll
        for (int mi = 0; mi < 4; mi++)
#pragma unroll
            for (int q = 0; q < 4; q++)
                acc[mi][q] = __builtin_amdgcn_mfma_f32_16x16x32_bf16(af[mi], bfr[q], acc[mi][q], 0, 0, 0);
    }
    const int rblk0 = r0 >> 4;
#pragma unroll
    for (int mi = 0; mi < 4; mi++) {
        int rowblk = rblk0 + wm * 4 + mi;
#pragma unroll
        for (int q = 0; q < 4; q++) {
            int qg = by * 8 + wn * 4 + q;
            uint2 o;
            o.x = (unsigned)f2bf(acc[mi][q][0]) | ((unsigned)f2bf(acc[mi][q][1]) << 16);
            o.y = (unsigned)f2bf(acc[mi][q][2]) | ((unsigned)f2bf(acc[mi][q][3]) << 16);
            *(uint2*)&xgp[(((size_t)rowblk * 64 + qg) * 64 + l) * 4] = o;
        }
    }
}

__global__ __launch_bounds__(256) void gemm_dual(const float* __restrict__ x,
                                                 const unsigned short* __restrict__ y0bf,
                                                 const unsigned short* __restrict__ Wp0,
                                                 const float* __restrict__ bias0,
                                                 const unsigned short* __restrict__ Wp1,
                                                 const float* __restrict__ bias1,
                                                 unsigned short* __restrict__ xgpA,
                                                 unsigned short* __restrict__ xgpB, int c0, int c1) {
    extern __shared__ short Albs[];  // 64 KB
    if (blockIdx.z == 0) {
        if (c0 < 0) return;
        gemm_body<true>(x, Wp0, bias0, xgpA, c0, Albs);
    } else {
        if (c1 < 0) return;
        gemm_body<false>(y0bf, Wp1, bias1, xgpB, c1, Albs);
    }
}

// ---------------- recurrent scan: R5 layout + NON-DRAINING raw barriers ----------------
// 32 WGs (16/layer), 1024 thr (16 waves). Wave w owns col-tile w: 4 gate tiles streamed per
// kk via global_load_lds (per-wave parity dbuf), Wd register-resident.
// KEY CHANGE vs R5: in-loop barriers are raw s_barrier with lgkmcnt-only waits — VMEM
// (y-stores, xg/dec prefetch, weight DMA) stays in flight across phases instead of being
// drained by __syncthreads' vmcnt(0). xg/dec prefetch issued in EW phase for max slack.
template <bool ISL0>
__device__ void rec_run(const unsigned short* __restrict__ xgp, const bf16x8* __restrict__ Whp8,
                        const bf16x8* __restrict__ Wdp8, const float* __restrict__ bd,
                        const float* __restrict__ dec_in, void* __restrict__ yout,
                        float* __restrict__ dec_out, unsigned short* __restrict__ h_state,
                        float* __restrict__ c_state, int chunk, int bblk, char* smem) {
    short* stage = (short*)smem;           // [2][16 waves][4 frags * 512 shorts] = 128 KB
    short* hb = (short*)(smem + 131072);   // [16][256] bf16
    short* cb = (short*)(smem + 139264);   // [16][256] bf16
    const int tid = threadIdx.x;           // 0..1023
    const int w = tid >> 6, l = tid & 63;
    const int lgrp = l >> 4, col = l & 15;
    const int b0 = bblk * 16;
    const int n = w * 16 + col;
    const float bdv = bd[n];

    bf16x8 wd[8];
#pragma unroll
    for (int kk = 0; kk < 8; kk++) wd[kk] = Wdp8[((size_t)w * 8 + kk) * 64 + l];

    float creg[4];
    if (chunk == 0) {
#pragma unroll
        for (int r = 0; r < 4; r++) creg[r] = 0.f;
        for (int i = tid; i < 4096; i += 1024) { hb[i] = 0; cb[i] = 0; }
    } else {
#pragma unroll
        for (int i = 0; i < 4; i++) {
            int idx = tid + i * 1024;
            int row = idx >> 8, nn = idx & 255;
            int sw = nn ^ ((row & 7) << 3);
            hb[row * 256 + sw] = (short)h_state[(size_t)(b0 + row) * H_ + nn];
            cb[row * 256 + sw] = (short)f2bf(c_state[(size_t)(b0 + row) * H_ + nn]);
        }
#pragma unroll
        for (int r = 0; r < 4; r++)
            creg[r] = c_state[(size_t)(b0 + lgrp * 4 + r) * H_ + n];
    }
    const uint2* xg8 = (const uint2*)xgp;
    uint2 xc[4], xn[4];
#pragma unroll
    for (int q = 0; q < 4; q++)
        xc[q] = xg8[((size_t)bblk * 64 + (q * 16 + w)) * 64 + l];
    float dn[4];
#pragma unroll
    for (int r = 0; r < 4; r++)
        dn[r] = dec_in[(size_t)(b0 + lgrp * 4 + r) * S_ + chunk * CHUNK];
    __syncthreads();  // chunk-start full barrier (once per chunk, cheap)

    short* swave0 = stage + ((size_t)w) * 2048;
    short* swave1 = stage + ((size_t)(16 + w)) * 2048;
#pragma unroll
    for (int q = 0; q < 4; q++)
        gload_lds16(Whp8 + ((size_t)(q * 16 + w) * 8 + 0) * 64 + l, swave0 + q * 512);

#pragma unroll 1
    for (int t = 0; t < CHUNK; ++t) {
        const int tg = chunk * CHUNK + t;
        float dcur[4];
#pragma unroll
        for (int r = 0; r < 4; r++) dcur[r] = dn[r];
        f32x4 csacc = {0.f, 0.f, 0.f, 0.f};
        f32x4 gacc[4];
#pragma unroll
        for (int q = 0; q < 4; q++) {
            uint2 v = xc[q];
            gacc[q][0] = bfbits_lo(v.x);
            gacc[q][1] = bfbits_hi(v.x);
            gacc[q][2] = bfbits_lo(v.y);
            gacc[q][3] = bfbits_hi(v.y);
        }
#pragma unroll
        for (int kk = 0; kk < 8; kk++) {
            __builtin_amdgcn_s_waitcnt(0x0F70);  // vmcnt(0): current DMA batch arrived
            __builtin_amdgcn_sched_barrier(0);
            const short* sbuf = (kk & 1) ? swave1 : swave0;
            const int ha = col * 256 + ((kk * 32 + lgrp * 8) ^ ((col & 7) << 3));
            bf16x8 hf = *(const bf16x8*)&hb[ha];
            bf16x8 cf = *(const bf16x8*)&cb[ha];
            csacc = __builtin_amdgcn_mfma_f32_16x16x32_bf16(cf, wd[kk], csacc, 0, 0, 0);
#pragma unroll
            for (int q = 0; q < 4; q++) {
                bf16x8 wf = *(const bf16x8*)&sbuf[q * 512 + l * 8];
                gacc[q] = __builtin_amdgcn_mfma_f32_16x16x32_bf16(hf, wf, gacc[q], 0, 0, 0);
            }
            const int kn = (kk + 1) & 7;  // kk=7 issues next step's kk0 into parity 0
            short* sdst = ((kk + 1) & 1) ? swave1 : swave0;
#pragma unroll
            for (int q = 0; q < 4; q++)
                gload_lds16(Whp8 + ((size_t)(q * 16 + w) * 8 + kn) * 64 + l, sdst + q * 512);
        }
        // barrier 1: all hb/cb ds_reads of this step retired (compiler lgkmcnt before MFMA).
        // Raw s_barrier — NO vmcnt drain; DMA/stores/prefetch stay in flight.
        __builtin_amdgcn_sched_barrier(0);
        __builtin_amdgcn_s_barrier();
        __builtin_amdgcn_sched_barrier(0);
        // prefetch next step's xg + dec now (EW below hides their latency)
        const int tn = (t + 1 < CHUNK) ? t + 1 : t;
        {
            int rb = tn * 16 + bblk;
#pragma unroll
            for (int q = 0; q < 4; q++)
                xn[q] = xg8[((size_t)rb * 64 + (q * 16 + w)) * 64 + l];
            int tgn = chunk * CHUNK + tn;
#pragma unroll
            for (int r = 0; r < 4; r++)
                dn[r] = dec_in[(size_t)(b0 + lgrp * 4 + r) * S_ + tgn];
        }
#pragma unroll
        for (int r = 0; r < 4; r++) {
            int row = lgrp * 4 + r;
            float cs = tanhf_(csacc[r] + bdv);
            float cadj = creg[r] - cs + cs * dcur[r];
            float iv = sigmoidf_(gacc[0][r]);
            float fv = sigmoidf_(gacc[1][r]);
            float ov = sigmoidf_(gacc[2][r]);
            float cd = tanhf_(gacc[3][r]);
            float cn = fv * cadj + iv * cd;
            float hn = ov * tanhf_(cn);
            creg[r] = cn;
            int sw = n ^ ((row & 7) << 3);
            unsigned short hnb = f2bf(hn);
            hb[row * 256 + sw] = (short)hnb;
            cb[row * 256 + sw] = (short)f2bf(cn);
            size_t yi = ((size_t)(b0 + row) * S_ + tg) * H_ + n;
            if constexpr (ISL0) {
                ((unsigned short*)yout)[yi] = hnb;
                if (w == 15 && col == 15)
                    dec_out[(size_t)(b0 + row) * S_ + tg] = 1.f / __logf(2.718281828459045f + hn);
            } else {
                ((float*)yout)[yi] = hn;
            }
            if (t == CHUNK - 1) {
                h_state[(size_t)(b0 + row) * H_ + n] = hnb;
                c_state[(size_t)(b0 + row) * H_ + n] = cn;
            }
        }
        // barrier 2: publish hb/cb writes — wait LDS ops only, then raw barrier.
        asm volatile("s_waitcnt lgkmcnt(0)" ::: "memory");
        __builtin_amdgcn_s_barrier();
        __builtin_amdgcn_sched_barrier(0);
#pragma unroll
        for (int q = 0; q < 4; q++) xc[q] = xn[q];
    }
}

__global__ __launch_bounds__(1024, 4) void rec_fused(
    const unsigned short* __restrict__ xgpA, const unsigned short* __restrict__ Whp0,
    const unsigned short* __restrict__ Wdp0, const float* __restrict__ bd0,
    const float* __restrict__ dec0, unsigned short* __restrict__ y0bf,
    float* __restrict__ dec1, unsigned short* __restrict__ hs0, float* __restrict__ cs0,
    const unsigned short* __restrict__ xgpB, const unsigned short* __restrict__ Whp1,
    const unsigned short* __restrict__ Wdp1, const float* __restrict__ bd1,
    float* __restrict__ y1, unsigned short* __restrict__ hs1, float* __restrict__ cs1,
    int c0, int c1) {
    extern __shared__ char smem[];
    int lay = blockIdx.x >> 4, bblk = blockIdx.x & 15;
    if (lay == 0) {
        if (c0 < 0) return;
        rec_run<true>(xgpA, (const bf16x8*)Whp0, (const bf16x8*)Wdp0, bd0, dec0, y0bf, dec1,
                      hs0, cs0, c0, bblk, smem);
    } else {
        if (c1 < 0) return;
        rec_run<false>(xgpB, (const bf16x8*)Whp1, (const bf16x8*)Wdp1, bd1, dec1, y1, nullptr,
                       hs1, cs1, c1, bblk, smem);
    }
}

__global__ void copy_tail(const unsigned short* __restrict__ h0, const float* __restrict__ c0,
                          const unsigned short* __restrict__ h1, const float* __restrict__ c1,
                          float* __restrict__ out) {
    int i = blockIdx.x * 256 + threadIdx.x;
    if (i >= 4 * 65536) return;
    int which = i >> 16, j = i & 65535;
    float v = which == 0 ? bf2f(h0[j]) : which == 1 ? c0[j] : which == 2 ? bf2f(h1[j]) : c1[j];
    out[i] = v;
}

extern "C" void kernel_launch(void* const* d_in, const int* in_sizes, int n_in, void* d_out,
                              int out_size, void* d_ws, size_t ws_size, hipStream_t stream) {
    (void)in_sizes; (void)n_in; (void)out_size; (void)ws_size;
    const float* x   = (const float*)d_in[0];
    const float* Wx0 = (const float*)d_in[1];
    const float* Wh0 = (const float*)d_in[2];
    const float* b0  = (const float*)d_in[3];
    const float* Wd0 = (const float*)d_in[4];
    const float* bd0 = (const float*)d_in[5];
    const float* Wx1 = (const float*)d_in[6];
    const float* Wh1 = (const float*)d_in[7];
    const float* b1  = (const float*)d_in[8];
    const float* Wd1 = (const float*)d_in[9];
    const float* bd1 = (const float*)d_in[10];

    char* ws = (char*)d_ws;
    size_t off = 0;
    auto take = [&](size_t bytes) { void* p = ws + off; off += (bytes + 255) & ~(size_t)255; return p; };
    unsigned short* wxp0 = (unsigned short*)take(524288);
    unsigned short* whp0 = (unsigned short*)take(524288);
    unsigned short* wdp0 = (unsigned short*)take(131072);
    unsigned short* wxp1 = (unsigned short*)take(524288);
    unsigned short* whp1 = (unsigned short*)take(524288);
    unsigned short* wdp1 = (unsigned short*)take(131072);
    float* dec0 = (float*)take(524288);
    float* dec1 = (float*)take(524288);
    unsigned short* hs0 = (unsigned short*)take(131072);
    float* cs0 = (float*)take(262144);
    unsigned short* hs1 = (unsigned short*)take(131072);
    float* cs1 = (float*)take(262144);
    unsigned short* y0bf = (unsigned short*)take(67108864);
    unsigned short* xgpA = (unsigned short*)take(16777216);
    unsigned short* xgpB = (unsigned short*)take(16777216);

    const size_t smem_rec = 147456;  // 128K stage + 8K hb + 8K cb
    (void)hipFuncSetAttribute(reinterpret_cast<const void*>(&rec_fused),
                              hipFuncAttributeMaxDynamicSharedMemorySize, (int)smem_rec);
    (void)hipFuncSetAttribute(reinterpret_cast<const void*>(&gemm_dual),
                              hipFuncAttributeMaxDynamicSharedMemorySize, 65536);

    prep_w<<<128, 256, 0, stream>>>(Wx0, wxp0, 64);
    prep_w<<<128, 256, 0, stream>>>(Wh0, whp0, 64);
    prep_w<<<32, 256, 0, stream>>>(Wd0, wdp0, 16);
    prep_w<<<128, 256, 0, stream>>>(Wx1, wxp1, 64);
    prep_w<<<128, 256, 0, stream>>>(Wh1, whp1, 64);
    prep_w<<<32, 256, 0, stream>>>(Wd1, wdp1, 16);
    prep_decay<<<512, 256, 0, stream>>>(x, dec0, B_ * S_);

    float* y1 = (float*)d_out;
    for (int s = 0; s <= NCHUNK; ++s) {
        int c0 = (s < NCHUNK) ? s : -1;
        int c1 = (s >= 1) ? s - 1 : -1;
        gemm_dual<<<dim3(64, 8, 2), 256, 65536, stream>>>(x, y0bf, wxp0, b0, wxp1, b1,
                                                          xgpA, xgpB, c0, c1);
        rec_fused<<<32, 1024, smem_rec, stream>>>(xgpA, whp0, wdp0, bd0, dec0, y0bf, dec1,
                                                  hs0, cs0, xgpB, whp1, wdp1, bd1, y1,
                                                  hs1, cs1, c0, c1);
    }
    copy_tail<<<1024, 256, 0, stream>>>(hs0, cs0, hs1, cs1, y1 + (size_t)B_ * S_ * H_);
}

// Round 10
// 4889.468 us; speedup vs baseline: 2.3373x; 1.5942x over previous
//
#include <hip/hip_runtime.h>
#include <stdint.h>

#define B_ 256
#define S_ 512
#define H_ 256
#define G_ 1024
#define CHUNK 32
#define NCHUNK (S_ / CHUNK)

typedef __attribute__((ext_vector_type(8))) short bf16x8;
typedef __attribute__((ext_vector_type(4))) float f32x4;

__device__ __forceinline__ unsigned short f2bf(float f) {
    unsigned u = __builtin_bit_cast(unsigned, f);
    unsigned r = u + 0x7fffu + ((u >> 16) & 1u);
    return (unsigned short)(r >> 16);
}
__device__ __forceinline__ float bf2f(unsigned short v) {
    return __builtin_bit_cast(float, (unsigned)v << 16);
}
__device__ __forceinline__ float bfbits_lo(unsigned v) {
    return __builtin_bit_cast(float, (unsigned)(v << 16));
}
__device__ __forceinline__ float bfbits_hi(unsigned v) {
    return __builtin_bit_cast(float, v & 0xffff0000u);
}
__device__ __forceinline__ float sigmoidf_(float x) { return 1.f / (1.f + __expf(-x)); }
__device__ __forceinline__ float tanhf_(float x) { return 2.f / (1.f + __expf(-2.f * x)) - 1.f; }

// ---------------- prep: weights -> fragment-major bf16 ----------------
// Wp[nt][kk][lane][i] = W[k][n], k = kk*32 + (lane>>4)*8 + i, n = nt*16 + (lane&15)
__global__ void prep_w(const float* __restrict__ W, unsigned short* __restrict__ Wp, int NT) {
    int tid = blockIdx.x * 256 + threadIdx.x;
    int total = NT * 8 * 64;
    if (tid >= total) return;
    int l = tid & 63, kk = (tid >> 6) & 7, nt = tid >> 9;
    int n = nt * 16 + (l & 15);
    int k0 = kk * 32 + (l >> 4) * 8;
    int N = NT * 16;
    unsigned short v[8];
#pragma unroll
    for (int i = 0; i < 8; i++) v[i] = f2bf(W[(size_t)(k0 + i) * N + n]);
    uint4 o;
    o.x = (unsigned)v[0] | ((unsigned)v[1] << 16);
    o.y = (unsigned)v[2] | ((unsigned)v[3] << 16);
    o.z = (unsigned)v[4] | ((unsigned)v[5] << 16);
    o.w = (unsigned)v[6] | ((unsigned)v[7] << 16);
    *(uint4*)(Wp + (size_t)tid * 8) = o;
}

__global__ void prep_decay(const float* __restrict__ x, float* __restrict__ dec, int n) {
    int i = blockIdx.x * 256 + threadIdx.x;
    if (i < n) dec[i] = 1.f / __logf(2.718281828459045f + x[(size_t)i * H_ + (H_ - 1)]);
}

// ---------------- xg GEMM body (unchanged) ----------------
template <bool SRCF32>
__device__ void gemm_body(const void* __restrict__ src, const unsigned short* __restrict__ Wp,
                          const float* __restrict__ bias, unsigned short* __restrict__ xgp,
                          int chunk, short* Albs) {
    const int tid = threadIdx.x;
    const int bx = blockIdx.x;
    const int by = blockIdx.y;
    const int r0 = bx * 128;
    const int t_loc = r0 >> 8;
    const int b0 = r0 & 255;
    const int sg = chunk * CHUNK + t_loc;
    {
        const int m = tid >> 1, kh = tid & 1;
        const size_t rowbase = ((size_t)(b0 + m) * S_ + sg) * H_ + kh * 128;
        if constexpr (SRCF32) {
            const float* p = (const float*)src + rowbase;
#pragma unroll
            for (int jo = 0; jo < 16; jo++) {
                int k = kh * 128 + jo * 8;
                float4 a = *(const float4*)(p + jo * 8);
                float4 b = *(const float4*)(p + jo * 8 + 4);
                int slot = ((m >> 4) * 8 + (k >> 5)) * 64 + ((m & 15) | (((k >> 3) & 3) << 4));
                uint4 o;
                o.x = (unsigned)f2bf(a.x) | ((unsigned)f2bf(a.y) << 16);
                o.y = (unsigned)f2bf(a.z) | ((unsigned)f2bf(a.w) << 16);
                o.z = (unsigned)f2bf(b.x) | ((unsigned)f2bf(b.y) << 16);
                o.w = (unsigned)f2bf(b.z) | ((unsigned)f2bf(b.w) << 16);
                *(uint4*)&Albs[slot * 8] = o;
            }
        } else {
            const unsigned short* p = (const unsigned short*)src + rowbase;
#pragma unroll
            for (int jo = 0; jo < 16; jo++) {
                int k = kh * 128 + jo * 8;
                uint4 o = *(const uint4*)(p + jo * 8);
                int slot = ((m >> 4) * 8 + (k >> 5)) * 64 + ((m & 15) | (((k >> 3) & 3) << 4));
                *(uint4*)&Albs[slot * 8] = o;
            }
        }
    }
    __syncthreads();
    const int w = tid >> 6, l = tid & 63;
    const int wm = w >> 1, wn = w & 1;
    const int col = l & 15;
    float bv[4];
#pragma unroll
    for (int q = 0; q < 4; q++) bv[q] = bias[(by * 8 + wn * 4 + q) * 16 + col];
    f32x4 acc[4][4];
#pragma unroll
    for (int mi = 0; mi < 4; mi++)
#pragma unroll
        for (int q = 0; q < 4; q++) {
            acc[mi][q][0] = bv[q]; acc[mi][q][1] = bv[q];
            acc[mi][q][2] = bv[q]; acc[mi][q][3] = bv[q];
        }
    const bf16x8* Wp8 = (const bf16x8*)Wp;
#pragma unroll
    for (int kk = 0; kk < 8; kk++) {
        bf16x8 af[4], bfr[4];
#pragma unroll
        for (int mi = 0; mi < 4; mi++)
            af[mi] = *(const bf16x8*)&Albs[(((wm * 4 + mi) * 8 + kk) * 64 + l) * 8];
#pragma unroll
        for (int q = 0; q < 4; q++)
            bfr[q] = Wp8[((size_t)(by * 8 + wn * 4 + q) * 8 + kk) * 64 + l];
#pragma unroll
        for (int mi = 0; mi < 4; mi++)
#pragma unroll
            for (int q = 0; q < 4; q++)
                acc[mi][q] = __builtin_amdgcn_mfma_f32_16x16x32_bf16(af[mi], bfr[q], acc[mi][q], 0, 0, 0);
    }
    const int rblk0 = r0 >> 4;
#pragma unroll
    for (int mi = 0; mi < 4; mi++) {
        int rowblk = rblk0 + wm * 4 + mi;
#pragma unroll
        for (int q = 0; q < 4; q++) {
            int qg = by * 8 + wn * 4 + q;
            uint2 o;
            o.x = (unsigned)f2bf(acc[mi][q][0]) | ((unsigned)f2bf(acc[mi][q][1]) << 16);
            o.y = (unsigned)f2bf(acc[mi][q][2]) | ((unsigned)f2bf(acc[mi][q][3]) << 16);
            *(uint2*)&xgp[(((size_t)rowblk * 64 + qg) * 64 + l) * 4] = o;
        }
    }
}

__global__ __launch_bounds__(256) void gemm_dual(const float* __restrict__ x,
                                                 const unsigned short* __restrict__ y0bf,
                                                 const unsigned short* __restrict__ Wp0,
                                                 const float* __restrict__ bias0,
                                                 const unsigned short* __restrict__ Wp1,
                                                 const float* __restrict__ bias1,
                                                 unsigned short* __restrict__ xgpA,
                                                 unsigned short* __restrict__ xgpB, int c0, int c1) {
    extern __shared__ short Albs[];  // 64 KB
    if (blockIdx.z == 0) {
        if (c0 < 0) return;
        gemm_body<true>(x, Wp0, bias0, xgpA, c0, Albs);
    } else {
        if (c1 < 0) return;
        gemm_body<false>(y0bf, Wp1, bias1, xgpB, c1, Albs);
    }
}

// ---------------- recurrent scan: global->VGPR weight streaming, no LDS round-trip ----------
// 32 WGs (16/layer), 1024 thr (16 waves). Wave w owns col-tile w. Weights stream straight
// into a 2-deep VGPR parity buffer (5 frags = 20 VGPR per parity); loads for kk+1 issued
// before kk's MFMAs so the compiler's counted vmcnt hides L2 latency. LDS holds only h/c
// (16 KB). Raw non-draining barriers (R9). Anti-LICM: laundered zero offset makes weight
// addresses formally t-variant so all 8 kk batches can't be hoisted into registers.
template <bool ISL0>
__device__ void rec_run(const unsigned short* __restrict__ xgp, const bf16x8* __restrict__ Whp8,
                        const bf16x8* __restrict__ Wdp8, const float* __restrict__ bd,
                        const float* __restrict__ dec_in, void* __restrict__ yout,
                        float* __restrict__ dec_out, unsigned short* __restrict__ h_state,
                        float* __restrict__ c_state, int chunk, int bblk, char* smem) {
    short* hb = (short*)smem;            // [16][256] bf16
    short* cb = (short*)(smem + 8192);   // [16][256] bf16
    const int tid = threadIdx.x;         // 0..1023
    const int w = tid >> 6, l = tid & 63;
    const int lgrp = l >> 4, col = l & 15;
    const int b0 = bblk * 16;
    const int n = w * 16 + col;
    const float bdv = bd[n];

    float creg[4];
    if (chunk == 0) {
#pragma unroll
        for (int r = 0; r < 4; r++) creg[r] = 0.f;
        for (int i = tid; i < 4096; i += 1024) { hb[i] = 0; cb[i] = 0; }
    } else {
#pragma unroll
        for (int i = 0; i < 4; i++) {
            int idx = tid + i * 1024;
            int row = idx >> 8, nn = idx & 255;
            int sw = nn ^ ((row & 7) << 3);
            hb[row * 256 + sw] = (short)h_state[(size_t)(b0 + row) * H_ + nn];
            cb[row * 256 + sw] = (short)f2bf(c_state[(size_t)(b0 + row) * H_ + nn]);
        }
#pragma unroll
        for (int r = 0; r < 4; r++)
            creg[r] = c_state[(size_t)(b0 + lgrp * 4 + r) * H_ + n];
    }
    const uint2* xg8 = (const uint2*)xgp;
    uint2 xc[4], xn[4];
#pragma unroll
    for (int q = 0; q < 4; q++)
        xc[q] = xg8[((size_t)bblk * 64 + (q * 16 + w)) * 64 + l];
    float dn[4];
#pragma unroll
    for (int r = 0; r < 4; r++)
        dn[r] = dec_in[(size_t)(b0 + lgrp * 4 + r) * S_ + chunk * CHUNK];
    __syncthreads();  // chunk-start full barrier

    // prologue: kk=0 weight batch into parity 0
    bf16x8 wfb[2][4], wdb[2];
#pragma unroll
    for (int q = 0; q < 4; q++) wfb[0][q] = Whp8[((size_t)(q * 16 + w) * 8 + 0) * 64 + l];
    wdb[0] = Wdp8[((size_t)w * 8 + 0) * 64 + l];

#pragma unroll 1
    for (int t = 0; t < CHUNK; ++t) {
        const int tg = chunk * CHUNK + t;
        // laundered zero: weight addresses become formally t-variant (blocks LICM hoist)
        unsigned tz = 0;
        asm volatile("" : "+v"(tz));
        const int lz = l + (int)tz;
        float dcur[4];
#pragma unroll
        for (int r = 0; r < 4; r++) dcur[r] = dn[r];
        f32x4 csacc = {0.f, 0.f, 0.f, 0.f};
        f32x4 gacc[4];
#pragma unroll
        for (int q = 0; q < 4; q++) {
            uint2 v = xc[q];
            gacc[q][0] = bfbits_lo(v.x);
            gacc[q][1] = bfbits_hi(v.x);
            gacc[q][2] = bfbits_lo(v.y);
            gacc[q][3] = bfbits_hi(v.y);
        }
#pragma unroll
        for (int kk = 0; kk < 8; kk++) {
            const int cur = kk & 1, nb = cur ^ 1;
            const int kn = (kk + 1) & 7;  // kk=7 reloads kk=0 for next step (L2-hot)
            // issue next batch (VGPR loads; compiler-counted vmcnt waits before first use)
#pragma unroll
            for (int q = 0; q < 4; q++)
                wfb[nb][q] = Whp8[((size_t)(q * 16 + w) * 8 + kn) * 64 + lz];
            wdb[nb] = Wdp8[((size_t)w * 8 + kn) * 64 + lz];
            const int ha = col * 256 + ((kk * 32 + lgrp * 8) ^ ((col & 7) << 3));
            bf16x8 hf = *(const bf16x8*)&hb[ha];
            bf16x8 cf = *(const bf16x8*)&cb[ha];
            csacc = __builtin_amdgcn_mfma_f32_16x16x32_bf16(cf, wdb[cur], csacc, 0, 0, 0);
#pragma unroll
            for (int q = 0; q < 4; q++)
                gacc[q] = __builtin_amdgcn_mfma_f32_16x16x32_bf16(hf, wfb[cur][q], gacc[q], 0, 0, 0);
        }
        // barrier 1: hb/cb reads of this step retired (lgkmcnt before MFMA use). Raw
        // s_barrier — no vmcnt drain; weight loads / stores / prefetch stay in flight.
        __builtin_amdgcn_sched_barrier(0);
        __builtin_amdgcn_s_barrier();
        __builtin_amdgcn_sched_barrier(0);
        // prefetch next step's xg + dec (EW below hides latency)
        const int tn = (t + 1 < CHUNK) ? t + 1 : t;
        {
            int rb = tn * 16 + bblk;
#pragma unroll
            for (int q = 0; q < 4; q++)
                xn[q] = xg8[((size_t)rb * 64 + (q * 16 + w)) * 64 + l];
            int tgn = chunk * CHUNK + tn;
#pragma unroll
            for (int r = 0; r < 4; r++)
                dn[r] = dec_in[(size_t)(b0 + lgrp * 4 + r) * S_ + tgn];
        }
#pragma unroll
        for (int r = 0; r < 4; r++) {
            int row = lgrp * 4 + r;
            float cs = tanhf_(csacc[r] + bdv);
            float cadj = creg[r] - cs + cs * dcur[r];
            float iv = sigmoidf_(gacc[0][r]);
            float fv = sigmoidf_(gacc[1][r]);
            float ov = sigmoidf_(gacc[2][r]);
            float cd = tanhf_(gacc[3][r]);
            float cn = fv * cadj + iv * cd;
            float hn = ov * tanhf_(cn);
            creg[r] = cn;
            int sw = n ^ ((row & 7) << 3);
            unsigned short hnb = f2bf(hn);
            hb[row * 256 + sw] = (short)hnb;
            cb[row * 256 + sw] = (short)f2bf(cn);
            size_t yi = ((size_t)(b0 + row) * S_ + tg) * H_ + n;
            if constexpr (ISL0) {
                ((unsigned short*)yout)[yi] = hnb;
                if (w == 15 && col == 15)
                    dec_out[(size_t)(b0 + row) * S_ + tg] = 1.f / __logf(2.718281828459045f + hn);
            } else {
                ((float*)yout)[yi] = hn;
            }
            if (t == CHUNK - 1) {
                h_state[(size_t)(b0 + row) * H_ + n] = hnb;
                c_state[(size_t)(b0 + row) * H_ + n] = cn;
            }
        }
        // barrier 2: publish hb/cb writes — LDS-only wait, then raw barrier.
        asm volatile("s_waitcnt lgkmcnt(0)" ::: "memory");
        __builtin_amdgcn_s_barrier();
        __builtin_amdgcn_sched_barrier(0);
#pragma unroll
        for (int q = 0; q < 4; q++) xc[q] = xn[q];
    }
}

__global__ __launch_bounds__(1024, 4) void rec_fused(
    const unsigned short* __restrict__ xgpA, const unsigned short* __restrict__ Whp0,
    const unsigned short* __restrict__ Wdp0, const float* __restrict__ bd0,
    const float* __restrict__ dec0, unsigned short* __restrict__ y0bf,
    float* __restrict__ dec1, unsigned short* __restrict__ hs0, float* __restrict__ cs0,
    const unsigned short* __restrict__ xgpB, const unsigned short* __restrict__ Whp1,
    const unsigned short* __restrict__ Wdp1, const float* __restrict__ bd1,
    float* __restrict__ y1, unsigned short* __restrict__ hs1, float* __restrict__ cs1,
    int c0, int c1) {
    extern __shared__ char smem[];
    int lay = blockIdx.x >> 4, bblk = blockIdx.x & 15;
    if (lay == 0) {
        if (c0 < 0) return;
        rec_run<true>(xgpA, (const bf16x8*)Whp0, (const bf16x8*)Wdp0, bd0, dec0, y0bf, dec1,
                      hs0, cs0, c0, bblk, smem);
    } else {
        if (c1 < 0) return;
        rec_run<false>(xgpB, (const bf16x8*)Whp1, (const bf16x8*)Wdp1, bd1, dec1, y1, nullptr,
                       hs1, cs1, c1, bblk, smem);
    }
}

__global__ void copy_tail(const unsigned short* __restrict__ h0, const float* __restrict__ c0,
                          const unsigned short* __restrict__ h1, const float* __restrict__ c1,
                          float* __restrict__ out) {
    int i = blockIdx.x * 256 + threadIdx.x;
    if (i >= 4 * 65536) return;
    int which = i >> 16, j = i & 65535;
    float v = which == 0 ? bf2f(h0[j]) : which == 1 ? c0[j] : which == 2 ? bf2f(h1[j]) : c1[j];
    out[i] = v;
}

extern "C" void kernel_launch(void* const* d_in, const int* in_sizes, int n_in, void* d_out,
                              int out_size, void* d_ws, size_t ws_size, hipStream_t stream) {
    (void)in_sizes; (void)n_in; (void)out_size; (void)ws_size;
    const float* x   = (const float*)d_in[0];
    const float* Wx0 = (const float*)d_in[1];
    const float* Wh0 = (const float*)d_in[2];
    const float* b0  = (const float*)d_in[3];
    const float* Wd0 = (const float*)d_in[4];
    const float* bd0 = (const float*)d_in[5];
    const float* Wx1 = (const float*)d_in[6];
    const float* Wh1 = (const float*)d_in[7];
    const float* b1  = (const float*)d_in[8];
    const float* Wd1 = (const float*)d_in[9];
    const float* bd1 = (const float*)d_in[10];

    char* ws = (char*)d_ws;
    size_t off = 0;
    auto take = [&](size_t bytes) { void* p = ws + off; off += (bytes + 255) & ~(size_t)255; return p; };
    unsigned short* wxp0 = (unsigned short*)take(524288);
    unsigned short* whp0 = (unsigned short*)take(524288);
    unsigned short* wdp0 = (unsigned short*)take(131072);
    unsigned short* wxp1 = (unsigned short*)take(524288);
    unsigned short* whp1 = (unsigned short*)take(524288);
    unsigned short* wdp1 = (unsigned short*)take(131072);
    float* dec0 = (float*)take(524288);
    float* dec1 = (float*)take(524288);
    unsigned short* hs0 = (unsigned short*)take(131072);
    float* cs0 = (float*)take(262144);
    unsigned short* hs1 = (unsigned short*)take(131072);
    float* cs1 = (float*)take(262144);
    unsigned short* y0bf = (unsigned short*)take(67108864);
    unsigned short* xgpA = (unsigned short*)take(16777216);
    unsigned short* xgpB = (unsigned short*)take(16777216);

    const size_t smem_rec = 16384;  // hb + cb only
    (void)hipFuncSetAttribute(reinterpret_cast<const void*>(&rec_fused),
                              hipFuncAttributeMaxDynamicSharedMemorySize, (int)smem_rec);
    (void)hipFuncSetAttribute(reinterpret_cast<const void*>(&gemm_dual),
                              hipFuncAttributeMaxDynamicSharedMemorySize, 65536);

    prep_w<<<128, 256, 0, stream>>>(Wx0, wxp0, 64);
    prep_w<<<128, 256, 0, stream>>>(Wh0, whp0, 64);
    prep_w<<<32, 256, 0, stream>>>(Wd0, wdp0, 16);
    prep_w<<<128, 256, 0, stream>>>(Wx1, wxp1, 64);
    prep_w<<<128, 256, 0, stream>>>(Wh1, whp1, 64);
    prep_w<<<32, 256, 0, stream>>>(Wd1, wdp1, 16);
    prep_decay<<<512, 256, 0, stream>>>(x, dec0, B_ * S_);

    float* y1 = (float*)d_out;
    for (int s = 0; s <= NCHUNK; ++s) {
        int c0 = (s < NCHUNK) ? s : -1;
        int c1 = (s >= 1) ? s - 1 : -1;
        gemm_dual<<<dim3(64, 8, 2), 256, 65536, stream>>>(x, y0bf, wxp0, b0, wxp1, b1,
                                                          xgpA, xgpB, c0, c1);
        rec_fused<<<32, 1024, smem_rec, stream>>>(xgpA, whp0, wdp0, bd0, dec0, y0bf, dec1,
                                                  hs0, cs0, xgpB, whp1, wdp1, bd1, y1,
                                                  hs1, cs1, c0, c1);
    }
    copy_tail<<<1024, 256, 0, stream>>>(hs0, cs0, hs1, cs1, y1 + (size_t)B_ * S_ * H_);
}

// Round 11
// 4863.703 us; speedup vs baseline: 2.3497x; 1.0053x over previous
//
#include <hip/hip_runtime.h>
#include <stdint.h>

#define B_ 256
#define S_ 512
#define H_ 256
#define G_ 1024
#define CHUNK 32
#define NCHUNK (S_ / CHUNK)

typedef __attribute__((ext_vector_type(8))) short bf16x8;
typedef __attribute__((ext_vector_type(4))) float f32x4;

__device__ __forceinline__ unsigned short f2bf(float f) {
    unsigned u = __builtin_bit_cast(unsigned, f);
    unsigned r = u + 0x7fffu + ((u >> 16) & 1u);
    return (unsigned short)(r >> 16);
}
__device__ __forceinline__ float bf2f(unsigned short v) {
    return __builtin_bit_cast(float, (unsigned)v << 16);
}
__device__ __forceinline__ float bfbits_lo(unsigned v) {
    return __builtin_bit_cast(float, (unsigned)(v << 16));
}
__device__ __forceinline__ float bfbits_hi(unsigned v) {
    return __builtin_bit_cast(float, v & 0xffff0000u);
}
__device__ __forceinline__ float sigmoidf_(float x) { return 1.f / (1.f + __expf(-x)); }
__device__ __forceinline__ float tanhf_(float x) { return 2.f / (1.f + __expf(-2.f * x)) - 1.f; }

// ---------------- prep: weights -> fragment-major bf16 ----------------
// Wp[nt][kk][lane][i] = W[k][n], k = kk*32 + (lane>>4)*8 + i, n = nt*16 + (lane&15)
__global__ void prep_w(const float* __restrict__ W, unsigned short* __restrict__ Wp, int NT) {
    int tid = blockIdx.x * 256 + threadIdx.x;
    int total = NT * 8 * 64;
    if (tid >= total) return;
    int l = tid & 63, kk = (tid >> 6) & 7, nt = tid >> 9;
    int n = nt * 16 + (l & 15);
    int k0 = kk * 32 + (l >> 4) * 8;
    int N = NT * 16;
    unsigned short v[8];
#pragma unroll
    for (int i = 0; i < 8; i++) v[i] = f2bf(W[(size_t)(k0 + i) * N + n]);
    uint4 o;
    o.x = (unsigned)v[0] | ((unsigned)v[1] << 16);
    o.y = (unsigned)v[2] | ((unsigned)v[3] << 16);
    o.z = (unsigned)v[4] | ((unsigned)v[5] << 16);
    o.w = (unsigned)v[6] | ((unsigned)v[7] << 16);
    *(uint4*)(Wp + (size_t)tid * 8) = o;
}

__global__ void prep_decay(const float* __restrict__ x, float* __restrict__ dec, int n) {
    int i = blockIdx.x * 256 + threadIdx.x;
    if (i < n) dec[i] = 1.f / __logf(2.718281828459045f + x[(size_t)i * H_ + (H_ - 1)]);
}

// ---------------- xg GEMM body (unchanged) ----------------
template <bool SRCF32>
__device__ void gemm_body(const void* __restrict__ src, const unsigned short* __restrict__ Wp,
                          const float* __restrict__ bias, unsigned short* __restrict__ xgp,
                          int chunk, short* Albs) {
    const int tid = threadIdx.x;
    const int bx = blockIdx.x;
    const int by = blockIdx.y;
    const int r0 = bx * 128;
    const int t_loc = r0 >> 8;
    const int b0 = r0 & 255;
    const int sg = chunk * CHUNK + t_loc;
    {
        const int m = tid >> 1, kh = tid & 1;
        const size_t rowbase = ((size_t)(b0 + m) * S_ + sg) * H_ + kh * 128;
        if constexpr (SRCF32) {
            const float* p = (const float*)src + rowbase;
#pragma unroll
            for (int jo = 0; jo < 16; jo++) {
                int k = kh * 128 + jo * 8;
                float4 a = *(const float4*)(p + jo * 8);
                float4 b = *(const float4*)(p + jo * 8 + 4);
                int slot = ((m >> 4) * 8 + (k >> 5)) * 64 + ((m & 15) | (((k >> 3) & 3) << 4));
                uint4 o;
                o.x = (unsigned)f2bf(a.x) | ((unsigned)f2bf(a.y) << 16);
                o.y = (unsigned)f2bf(a.z) | ((unsigned)f2bf(a.w) << 16);
                o.z = (unsigned)f2bf(b.x) | ((unsigned)f2bf(b.y) << 16);
                o.w = (unsigned)f2bf(b.z) | ((unsigned)f2bf(b.w) << 16);
                *(uint4*)&Albs[slot * 8] = o;
            }
        } else {
            const unsigned short* p = (const unsigned short*)src + rowbase;
#pragma unroll
            for (int jo = 0; jo < 16; jo++) {
                int k = kh * 128 + jo * 8;
                uint4 o = *(const uint4*)(p + jo * 8);
                int slot = ((m >> 4) * 8 + (k >> 5)) * 64 + ((m & 15) | (((k >> 3) & 3) << 4));
                *(uint4*)&Albs[slot * 8] = o;
            }
        }
    }
    __syncthreads();
    const int w = tid >> 6, l = tid & 63;
    const int wm = w >> 1, wn = w & 1;
    const int col = l & 15;
    float bv[4];
#pragma unroll
    for (int q = 0; q < 4; q++) bv[q] = bias[(by * 8 + wn * 4 + q) * 16 + col];
    f32x4 acc[4][4];
#pragma unroll
    for (int mi = 0; mi < 4; mi++)
#pragma unroll
        for (int q = 0; q < 4; q++) {
            acc[mi][q][0] = bv[q]; acc[mi][q][1] = bv[q];
            acc[mi][q][2] = bv[q]; acc[mi][q][3] = bv[q];
        }
    const bf16x8* Wp8 = (const bf16x8*)Wp;
#pragma unroll
    for (int kk = 0; kk < 8; kk++) {
        bf16x8 af[4], bfr[4];
#pragma unroll
        for (int mi = 0; mi < 4; mi++)
            af[mi] = *(const bf16x8*)&Albs[(((wm * 4 + mi) * 8 + kk) * 64 + l) * 8];
#pragma unroll
        for (int q = 0; q < 4; q++)
            bfr[q] = Wp8[((size_t)(by * 8 + wn * 4 + q) * 8 + kk) * 64 + l];
#pragma unroll
        for (int mi = 0; mi < 4; mi++)
#pragma unroll
            for (int q = 0; q < 4; q++)
                acc[mi][q] = __builtin_amdgcn_mfma_f32_16x16x32_bf16(af[mi], bfr[q], acc[mi][q], 0, 0, 0);
    }
    const int rblk0 = r0 >> 4;
#pragma unroll
    for (int mi = 0; mi < 4; mi++) {
        int rowblk = rblk0 + wm * 4 + mi;
#pragma unroll
        for (int q = 0; q < 4; q++) {
            int qg = by * 8 + wn * 4 + q;
            uint2 o;
            o.x = (unsigned)f2bf(acc[mi][q][0]) | ((unsigned)f2bf(acc[mi][q][1]) << 16);
            o.y = (unsigned)f2bf(acc[mi][q][2]) | ((unsigned)f2bf(acc[mi][q][3]) << 16);
            *(uint2*)&xgp[(((size_t)rowblk * 64 + qg) * 64 + l) * 4] = o;
        }
    }
}

__global__ __launch_bounds__(256) void gemm_dual(const float* __restrict__ x,
                                                 const unsigned short* __restrict__ y0bf,
                                                 const unsigned short* __restrict__ Wp0,
                                                 const float* __restrict__ bias0,
                                                 const unsigned short* __restrict__ Wp1,
                                                 const float* __restrict__ bias1,
                                                 unsigned short* __restrict__ xgpA,
                                                 unsigned short* __restrict__ xgpB, int c0, int c1) {
    extern __shared__ short Albs[];  // 64 KB
    if (blockIdx.z == 0) {
        if (c0 < 0) return;
        gemm_body<true>(x, Wp0, bias0, xgpA, c0, Albs);
    } else {
        if (c1 < 0) return;
        gemm_body<false>(y0bf, Wp1, bias1, xgpB, c1, Albs);
    }
}

// ---------------- recurrent scan: VGPR weight streaming + single barrier/step ----------
// 32 WGs (16/layer), 1024 thr (16 waves). Wave w owns col-tile w. Wh streams into a 2-deep
// VGPR parity buffer (compiler-counted vmcnt waits); Wd chunk-resident in VGPRs. h/c in
// LDS parity double buffer: step t reads parity t&1, writes (t&1)^1 -> ONE barrier/step.
// EW is register-only and runs before the barrier; xg/dec prefetch issued before EW so the
// L2 port stays busy through the EW window. SGPR-side launder blocks weight-load hoisting
// without per-lane address recomputation.
template <bool ISL0>
__device__ void rec_run(const unsigned short* __restrict__ xgp, const bf16x8* __restrict__ Whp8,
                        const bf16x8* __restrict__ Wdp8, const float* __restrict__ bd,
                        const float* __restrict__ dec_in, void* __restrict__ yout,
                        float* __restrict__ dec_out, unsigned short* __restrict__ h_state,
                        float* __restrict__ c_state, int chunk, int bblk, char* smem) {
    // LDS: [parity][16 rows][256 cols] bf16 for h and c  (2*16KB = 32 KB)
    const int tid = threadIdx.x;         // 0..1023
    const int w = tid >> 6, l = tid & 63;
    const int lgrp = l >> 4, col = l & 15;
    const int b0 = bblk * 16;
    const int n = w * 16 + col;
    const float bdv = bd[n];

    // Wd tile resident in registers for the whole chunk (32 VGPR)
    bf16x8 wd[8];
#pragma unroll
    for (int kk = 0; kk < 8; kk++) wd[kk] = Wdp8[((size_t)w * 8 + kk) * 64 + l];

    float creg[4];
    {
        short* hb0 = (short*)smem;            // parity 0 h
        short* cb0 = (short*)(smem + 8192);   // parity 0 c
        if (chunk == 0) {
#pragma unroll
            for (int r = 0; r < 4; r++) creg[r] = 0.f;
            for (int i = tid; i < 4096; i += 1024) { hb0[i] = 0; cb0[i] = 0; }
        } else {
#pragma unroll
            for (int i = 0; i < 4; i++) {
                int idx = tid + i * 1024;
                int row = idx >> 8, nn = idx & 255;
                int sw = nn ^ ((row & 7) << 3);
                hb0[row * 256 + sw] = (short)h_state[(size_t)(b0 + row) * H_ + nn];
                cb0[row * 256 + sw] = (short)f2bf(c_state[(size_t)(b0 + row) * H_ + nn]);
            }
#pragma unroll
            for (int r = 0; r < 4; r++)
                creg[r] = c_state[(size_t)(b0 + lgrp * 4 + r) * H_ + n];
        }
    }
    const uint2* xg8 = (const uint2*)xgp;
    uint2 xc[4], xn[4];
#pragma unroll
    for (int q = 0; q < 4; q++)
        xc[q] = xg8[((size_t)bblk * 64 + (q * 16 + w)) * 64 + l];
    float dn[4];
#pragma unroll
    for (int r = 0; r < 4; r++)
        dn[r] = dec_in[(size_t)(b0 + lgrp * 4 + r) * S_ + chunk * CHUNK];
    __syncthreads();  // chunk-start full barrier (staging visible)

    // prologue: Wh kk=0 batch into parity 0 of the VGPR stream buffer
    bf16x8 wfb[2][4];
#pragma unroll
    for (int q = 0; q < 4; q++) wfb[0][q] = Whp8[((size_t)(q * 16 + w) * 8 + 0) * 64 + l];

#pragma unroll 1
    for (int t = 0; t < CHUNK; ++t) {
        const int tg = chunk * CHUNK + t;
        const int par = t & 1;
        const short* hb = (const short*)(smem + par * 16384);
        const short* cb = (const short*)(smem + par * 16384 + 8192);
        short* hx = (short*)(smem + (par ^ 1) * 16384);
        short* cx = (short*)(smem + (par ^ 1) * 16384 + 8192);
        // SGPR-side launder: weight loads become formally t-variant (no hoist), but the
        // per-lane offset stays loop-invariant -> addresses are SALU work only.
        const bf16x8* WhpT;
        {
            unsigned long long tz = 0;
            asm volatile("" : "+s"(tz));
            WhpT = (const bf16x8*)((const char*)Whp8 + tz);
        }
        float dcur[4];
#pragma unroll
        for (int r = 0; r < 4; r++) dcur[r] = dn[r];
        f32x4 csacc = {0.f, 0.f, 0.f, 0.f};
        f32x4 gacc[4];
#pragma unroll
        for (int q = 0; q < 4; q++) {
            uint2 v = xc[q];
            gacc[q][0] = bfbits_lo(v.x);
            gacc[q][1] = bfbits_hi(v.x);
            gacc[q][2] = bfbits_lo(v.y);
            gacc[q][3] = bfbits_hi(v.y);
        }
#pragma unroll
        for (int kk = 0; kk < 8; kk++) {
            const int cur = kk & 1, nb = cur ^ 1;
            const int kn = (kk + 1) & 7;  // kk=7 issues next step's kk=0 (same data, L2-hot)
#pragma unroll
            for (int q = 0; q < 4; q++)
                wfb[nb][q] = WhpT[((size_t)(q * 16 + w) * 8 + kn) * 64 + l];
            const int ha = col * 256 + ((kk * 32 + lgrp * 8) ^ ((col & 7) << 3));
            bf16x8 hf = *(const bf16x8*)&hb[ha];
            bf16x8 cf = *(const bf16x8*)&cb[ha];
            csacc = __builtin_amdgcn_mfma_f32_16x16x32_bf16(cf, wd[kk], csacc, 0, 0, 0);
#pragma unroll
            for (int q = 0; q < 4; q++)
                gacc[q] = __builtin_amdgcn_mfma_f32_16x16x32_bf16(hf, wfb[cur][q], gacc[q], 0, 0, 0);
        }
        // prefetch next step's xg + dec now (EW below hides their latency; port stays busy)
        const int tn = (t + 1 < CHUNK) ? t + 1 : t;
        {
            int rb = tn * 16 + bblk;
#pragma unroll
            for (int q = 0; q < 4; q++)
                xn[q] = xg8[((size_t)rb * 64 + (q * 16 + w)) * 64 + l];
            int tgn = chunk * CHUNK + tn;
#pragma unroll
            for (int r = 0; r < 4; r++)
                dn[r] = dec_in[(size_t)(b0 + lgrp * 4 + r) * S_ + tgn];
        }
        // EW (register-only) + LDS writes to the OTHER parity + global stores
#pragma unroll
        for (int r = 0; r < 4; r++) {
            int row = lgrp * 4 + r;
            float cs = tanhf_(csacc[r] + bdv);
            float cadj = creg[r] - cs + cs * dcur[r];
            float iv = sigmoidf_(gacc[0][r]);
            float fv = sigmoidf_(gacc[1][r]);
            float ov = sigmoidf_(gacc[2][r]);
            float cd = tanhf_(gacc[3][r]);
            float cn = fv * cadj + iv * cd;
            float hn = ov * tanhf_(cn);
            creg[r] = cn;
            int sw = n ^ ((row & 7) << 3);
            unsigned short hnb = f2bf(hn);
            hx[row * 256 + sw] = (short)hnb;
            cx[row * 256 + sw] = (short)f2bf(cn);
            size_t yi = ((size_t)(b0 + row) * S_ + tg) * H_ + n;
            if constexpr (ISL0) {
                ((unsigned short*)yout)[yi] = hnb;
                if (w == 15 && col == 15)
                    dec_out[(size_t)(b0 + row) * S_ + tg] = 1.f / __logf(2.718281828459045f + hn);
            } else {
                ((float*)yout)[yi] = hn;
            }
            if (t == CHUNK - 1) {
                h_state[(size_t)(b0 + row) * H_ + n] = hnb;
                c_state[(size_t)(b0 + row) * H_ + n] = cn;
            }
        }
        // SINGLE barrier per step: publish LDS writes (lgkm only — no VMEM drain).
        asm volatile("s_waitcnt lgkmcnt(0)" ::: "memory");
        __builtin_amdgcn_s_barrier();
        __builtin_amdgcn_sched_barrier(0);
#pragma unroll
        for (int q = 0; q < 4; q++) xc[q] = xn[q];
    }
}

__global__ __launch_bounds__(1024, 4) void rec_fused(
    const unsigned short* __restrict__ xgpA, const unsigned short* __restrict__ Whp0,
    const unsigned short* __restrict__ Wdp0, const float* __restrict__ bd0,
    const float* __restrict__ dec0, unsigned short* __restrict__ y0bf,
    float* __restrict__ dec1, unsigned short* __restrict__ hs0, float* __restrict__ cs0,
    const unsigned short* __restrict__ xgpB, const unsigned short* __restrict__ Whp1,
    const unsigned short* __restrict__ Wdp1, const float* __restrict__ bd1,
    float* __restrict__ y1, unsigned short* __restrict__ hs1, float* __restrict__ cs1,
    int c0, int c1) {
    extern __shared__ char smem[];
    int lay = blockIdx.x >> 4, bblk = blockIdx.x & 15;
    if (lay == 0) {
        if (c0 < 0) return;
        rec_run<true>(xgpA, (const bf16x8*)Whp0, (const bf16x8*)Wdp0, bd0, dec0, y0bf, dec1,
                      hs0, cs0, c0, bblk, smem);
    } else {
        if (c1 < 0) return;
        rec_run<false>(xgpB, (const bf16x8*)Whp1, (const bf16x8*)Wdp1, bd1, dec1, y1, nullptr,
                       hs1, cs1, c1, bblk, smem);
    }
}

__global__ void copy_tail(const unsigned short* __restrict__ h0, const float* __restrict__ c0,
                          const unsigned short* __restrict__ h1, const float* __restrict__ c1,
                          float* __restrict__ out) {
    int i = blockIdx.x * 256 + threadIdx.x;
    if (i >= 4 * 65536) return;
    int which = i >> 16, j = i & 65535;
    float v = which == 0 ? bf2f(h0[j]) : which == 1 ? c0[j] : which == 2 ? bf2f(h1[j]) : c1[j];
    out[i] = v;
}

extern "C" void kernel_launch(void* const* d_in, const int* in_sizes, int n_in, void* d_out,
                              int out_size, void* d_ws, size_t ws_size, hipStream_t stream) {
    (void)in_sizes; (void)n_in; (void)out_size; (void)ws_size;
    const float* x   = (const float*)d_in[0];
    const float* Wx0 = (const float*)d_in[1];
    const float* Wh0 = (const float*)d_in[2];
    const float* b0  = (const float*)d_in[3];
    const float* Wd0 = (const float*)d_in[4];
    const float* bd0 = (const float*)d_in[5];
    const float* Wx1 = (const float*)d_in[6];
    const float* Wh1 = (const float*)d_in[7];
    const float* b1  = (const float*)d_in[8];
    const float* Wd1 = (const float*)d_in[9];
    const float* bd1 = (const float*)d_in[10];

    char* ws = (char*)d_ws;
    size_t off = 0;
    auto take = [&](size_t bytes) { void* p = ws + off; off += (bytes + 255) & ~(size_t)255; return p; };
    unsigned short* wxp0 = (unsigned short*)take(524288);
    unsigned short* whp0 = (unsigned short*)take(524288);
    unsigned short* wdp0 = (unsigned short*)take(131072);
    unsigned short* wxp1 = (unsigned short*)take(524288);
    unsigned short* whp1 = (unsigned short*)take(524288);
    unsigned short* wdp1 = (unsigned short*)take(131072);
    float* dec0 = (float*)take(524288);
    float* dec1 = (float*)take(524288);
    unsigned short* hs0 = (unsigned short*)take(131072);
    float* cs0 = (float*)take(262144);
    unsigned short* hs1 = (unsigned short*)take(131072);
    float* cs1 = (float*)take(262144);
    unsigned short* y0bf = (unsigned short*)take(67108864);
    unsigned short* xgpA = (unsigned short*)take(16777216);
    unsigned short* xgpB = (unsigned short*)take(16777216);

    const size_t smem_rec = 32768;  // h/c parity double buffer
    (void)hipFuncSetAttribute(reinterpret_cast<const void*>(&rec_fused),
                              hipFuncAttributeMaxDynamicSharedMemorySize, (int)smem_rec);
    (void)hipFuncSetAttribute(reinterpret_cast<const void*>(&gemm_dual),
                              hipFuncAttributeMaxDynamicSharedMemorySize, 65536);

    prep_w<<<128, 256, 0, stream>>>(Wx0, wxp0, 64);
    prep_w<<<128, 256, 0, stream>>>(Wh0, whp0, 64);
    prep_w<<<32, 256, 0, stream>>>(Wd0, wdp0, 16);
    prep_w<<<128, 256, 0, stream>>>(Wx1, wxp1, 64);
    prep_w<<<128, 256, 0, stream>>>(Wh1, whp1, 64);
    prep_w<<<32, 256, 0, stream>>>(Wd1, wdp1, 16);
    prep_decay<<<512, 256, 0, stream>>>(x, dec0, B_ * S_);

    float* y1 = (float*)d_out;
    for (int s = 0; s <= NCHUNK; ++s) {
        int c0 = (s < NCHUNK) ? s : -1;
        int c1 = (s >= 1) ? s - 1 : -1;
        gemm_dual<<<dim3(64, 8, 2), 256, 65536, stream>>>(x, y0bf, wxp0, b0, wxp1, b1,
                                                          xgpA, xgpB, c0, c1);
        rec_fused<<<32, 1024, smem_rec, stream>>>(xgpA, whp0, wdp0, bd0, dec0, y0bf, dec1,
                                                  hs0, cs0, xgpB, whp1, wdp1, bd1, y1,
                                                  hs1, cs1, c0, c1);
    }
    copy_tail<<<1024, 256, 0, stream>>>(hs0, cs0, hs1, cs1, y1 + (size_t)B_ * S_ * H_);
}